// Round 1
// baseline (293.347 us; speedup 1.0000x reference)
//
#include <hip/hip_runtime.h>
#include <math.h>

#define BS 1024
#define AA 3072
#define DD 2048

// One wave (64 lanes) per output row: y[row] = act(dot(W[row,:], x) + b[row]).
// IN_DIM compile-time so the float4 load loop fully unrolls (12 or 8 iters)
// giving many outstanding 16B loads per lane. ACT: 0=none, 1=tanh, 2=tanhshrink.
template<int IN_DIM, int ACT>
__global__ __launch_bounds__(256) void matvec_act(
    const float* __restrict__ W, const float* __restrict__ b,
    const float* __restrict__ x, float* __restrict__ y,
    float* __restrict__ y2, int out_dim)
{
    int row  = (int)((blockIdx.x * blockDim.x + threadIdx.x) >> 6);
    int lane = (int)(threadIdx.x & 63);
    if (row >= out_dim) return;

    const float4* __restrict__ Wr = (const float4*)(W + (size_t)row * IN_DIM);
    const float4* __restrict__ xv = (const float4*)x;

    constexpr int N4 = IN_DIM / 4;       // float4 count per row
    float sum = 0.f;
#pragma unroll
    for (int it = 0; it < N4 / 64; ++it) {
        int i = lane + it * 64;          // coalesced: consecutive lanes -> consecutive float4
        float4 w4 = Wr[i];
        float4 x4 = xv[i];
        sum += w4.x * x4.x + w4.y * x4.y + w4.z * x4.z + w4.w * x4.w;
    }

#pragma unroll
    for (int off = 32; off; off >>= 1) sum += __shfl_down(sum, off);

    if (lane == 0) {
        float v = sum + b[row];
        if (ACT == 1)      v = tanhf(v);
        else if (ACT == 2) v = v - tanhf(v);   // Tanhshrink
        y[row] = v;
        if (y2) y2[row] = v;                    // extra copy (lat_repr output)
    }
}

// Pairwise Euclidean distances, 3-dim points, a:[1024,3] -> out:[1024*1024]
__global__ __launch_bounds__(256) void pdist3_kernel(
    const float* __restrict__ a, float* __restrict__ out)
{
    int idx = (int)(blockIdx.x * blockDim.x + threadIdx.x);
    int i = idx >> 10, j = idx & 1023;
    float d0 = a[3 * i + 0] - a[3 * j + 0];
    float d1 = a[3 * i + 1] - a[3 * j + 1];
    float d2 = a[3 * i + 2] - a[3 * j + 2];
    out[idx] = sqrtf(d0 * d0 + d1 * d1 + d2 * d2);
}

// Pairwise Euclidean distances, 2-dim points, a:[1024,2] -> out:[1024*1024]
__global__ __launch_bounds__(256) void pdist2_kernel(
    const float* __restrict__ a, float* __restrict__ out)
{
    int idx = (int)(blockIdx.x * blockDim.x + threadIdx.x);
    int i = idx >> 10, j = idx & 1023;
    float d0 = a[2 * i + 0] - a[2 * j + 0];
    float d1 = a[2 * i + 1] - a[2 * j + 1];
    out[idx] = sqrtf(d0 * d0 + d1 * d1);
}

extern "C" void kernel_launch(void* const* d_in, const int* in_sizes, int n_in,
                              void* d_out, int out_size, void* d_ws, size_t ws_size,
                              hipStream_t stream)
{
    const float* x   = (const float*)d_in[0];
    const float* ew1 = (const float*)d_in[1];  const float* eb1 = (const float*)d_in[2];
    const float* ew2 = (const float*)d_in[3];  const float* eb2 = (const float*)d_in[4];
    const float* ew3 = (const float*)d_in[5];  const float* eb3 = (const float*)d_in[6];
    const float* ew4 = (const float*)d_in[7];  const float* eb4 = (const float*)d_in[8];
    const float* dw1 = (const float*)d_in[9];  const float* db1 = (const float*)d_in[10];
    const float* dw2 = (const float*)d_in[11]; const float* db2 = (const float*)d_in[12];
    const float* dw3 = (const float*)d_in[13]; const float* db3 = (const float*)d_in[14];
    const float* dw4 = (const float*)d_in[15]; const float* db4 = (const float*)d_in[16];

    float* out      = (float*)d_out;
    float* out_y    = out;                     // output        [3072]
    float* out_ind  = out + AA;                // in_diff_sum   [1024*1024]
    float* out_lat  = out_ind + BS * BS;       // lat_diff_sum  [1024*1024]
    float* out_rep  = out_lat + BS * BS;       // lat_repr      [2048]

    float* ws = (float*)d_ws;
    float* h1 = ws;            // [3072]
    float* h2 = h1 + AA;       // [3072]
    float* h3 = h2 + AA;       // [3072]
    float* yy = h3 + AA;       // [2048]
    float* g1 = yy + DD;       // [3072]
    float* g2 = g1 + AA;       // [3072]
    float* g3 = g2 + AA;       // [3072]

    dim3 blk(256);

    // in_diff depends only on x — launch first
    pdist3_kernel<<<BS * BS / 256, blk, 0, stream>>>(x, out_ind);

    // encoder
    matvec_act<AA, 1><<<AA / 4, blk, 0, stream>>>(ew1, eb1, x,  h1, nullptr, AA);
    matvec_act<AA, 1><<<AA / 4, blk, 0, stream>>>(ew2, eb2, h1, h2, nullptr, AA);
    matvec_act<AA, 0><<<AA / 4, blk, 0, stream>>>(ew3, eb3, h2, h3, nullptr, AA);
    matvec_act<AA, 2><<<DD / 4, blk, 0, stream>>>(ew4, eb4, h3, yy, out_rep, DD);

    // lat_diff on y
    pdist2_kernel<<<BS * BS / 256, blk, 0, stream>>>(yy, out_lat);

    // decoder
    matvec_act<DD, 1><<<AA / 4, blk, 0, stream>>>(dw1, db1, yy, g1, nullptr, AA);
    matvec_act<AA, 1><<<AA / 4, blk, 0, stream>>>(dw2, db2, g1, g2, nullptr, AA);
    matvec_act<AA, 0><<<AA / 4, blk, 0, stream>>>(dw3, db3, g2, g3, nullptr, AA);
    matvec_act<AA, 1><<<AA / 4, blk, 0, stream>>>(dw4, db4, g3, out_y, nullptr, AA);
}